// Round 6
// baseline (70.194 us; speedup 1.0000x reference)
//
#include <hip/hip_runtime.h>

// ---- problem constants (match reference) ----
constexpr int B = 4, N = 4096;       // H*W = 64*64
constexpr int CCH = 13;              // 5 + NC
constexpr float LINE_W = 30.0f;
constexpr double EPS = 1e-05;
constexpr double DICE_W = 5.0;
constexpr int BCAP = 1024;           // per-(e,b,class) bucket capacity (expected ~256)
constexpr int NPAIRB = 2304;         // pair grid: 2048 pushall + 256 bucket blocks

// ---- ws layout (float-indexed) ----
constexpr int EWP_OFF   = 0;                  // [11][256] elemwise per-wave partials
constexpr int PA_OFF    = 2816;               // [2048] pushall per-block partials
constexpr int BP_OFF    = 4864;               // [256][2] bucket per-block partials (pull, pushsame)
constexpr int CURS_OFF  = 5376;               // [64] int class histograms
constexpr int VCURS_OFF = 5440;               // [8] int valid counts
constexpr int DONE_OFF  = 5448;               // [1] int done-counter (reset by prep)
constexpr int BUCK_OFF  = 5632;               // [64][BCAP] class buckets (NaN padded to 256-mult)
constexpr int VC_OFF    = BUCK_OFF + 64 * BCAP;   // [8][4096] compact valid values (NaN padded)

__device__ inline float logsig(float x) {
    return fminf(x, 0.f) - log1pf(expf(-fabsf(x)));
}
__device__ inline float wave_reduce(float v) {
    #pragma unroll
    for (int off = 32; off > 0; off >>= 1) v += __shfl_down(v, off, 64);
    return v;
}
__device__ inline double wave_reduce_d(double v) {
    #pragma unroll
    for (int off = 32; off > 0; off >>= 1) v += __shfl_down(v, off, 64);
    return v;
}
__device__ inline float rdlane(float v, int k) {
    return __uint_as_float(__builtin_amdgcn_readlane(__float_as_uint(v), k));
}

// ---------------- Kernel 1: compact (blocks 0..7) + elementwise (blocks 8..23) ---
__global__ __launch_bounds__(1024) void prep_kernel(
        const float* __restrict__ outs, const float* __restrict__ gconf,
        const float* __restrict__ gox,  const float* __restrict__ goy,
        const int*   __restrict__ lidx, const int*   __restrict__ ign,
        const int*   __restrict__ fg,   const int*   __restrict__ lid,
        const float* __restrict__ gcls, float* __restrict__ ws) {
    const int tid = threadIdx.x, ln = tid & 63;

    if (blockIdx.x < 8) {
        // ---- compaction/bucketing for eb = blockIdx.x ----
        const int eb = blockIdx.x, e = eb >> 2, b = eb & 3;
        const int* gsrc = e ? lid : lidx;
        const float* pch = outs + ((size_t)b * CCH + 3 + e) * N;

        __shared__ int lcurs[9];            // 8 class cursors + 1 valid cursor
        if (tid < 9) lcurs[tid] = 0;
        if (eb == 0 && tid == 16) *(int*)(ws + DONE_OFF) = 0;   // reset done-counter
        __syncthreads();

        #pragma unroll
        for (int it = 0; it < 4; ++it) {
            const int n = it * 1024 + tid;
            const bool v = fg[b * N + n] > 0;
            const float val = pch[n];
            const int cc = gsrc[b * N + n] & 7;
            const unsigned long long below = (1ull << ln) - 1ull;
            const unsigned long long vm = __ballot(v);

            int mycnt = 0;      // lanes 0..7: class counts; lane 8: valid count
            int myrank = 0;     // this thread's rank within its class mask
            #pragma unroll
            for (int c = 0; c < 8; ++c) {
                const unsigned long long m = __ballot(v && cc == c);
                const int cnt = __popcll(m);
                if (ln == c) mycnt = cnt;
                if (cc == c) myrank = __popcll(m & below);
            }
            if (ln == 8) mycnt = __popcll(vm);
            const int myvrank = __popcll(vm & below);

            int abase = 0;
            if (ln < 9) abase = atomicAdd(&lcurs[ln], mycnt);   // 9 lanes, parallel banks
            const int cbase = __shfl(abase, cc, 64);
            const int vbase = __shfl(abase, 8, 64);

            if (v) {
                ws[VC_OFF + eb * 4096 + vbase + myvrank] = val;
                const int slot = cbase + myrank;
                if (slot < BCAP) ws[BUCK_OFF + (eb * 8 + cc) * BCAP + slot] = val;
            }
        }
        __syncthreads();

        // publish cursors + NaN-pad tails up to next 256 multiple
        int* curs  = (int*)(ws + CURS_OFF);
        int* vcurs = (int*)(ws + VCURS_OFF);
        const float QNAN = __int_as_float(0x7FC00000);
        if (tid < 8) curs[eb * 8 + tid] = min(lcurs[tid], BCAP);
        if (tid == 8) vcurs[eb] = lcurs[8];
        #pragma unroll
        for (int c = 0; c < 8; ++c) {
            const int mm = min(lcurs[c], BCAP);
            const int pad = ((mm + 255) & ~255) - mm;
            if (tid < pad) ws[BUCK_OFF + (eb * 8 + c) * BCAP + mm + tid] = QNAN;
        }
        const int mv = lcurs[8];
        const int padv = ((mv + 255) & ~255) - mv;
        if (tid < padv && mv + tid < 4096) ws[VC_OFF + eb * 4096 + mv + tid] = QNAN;
    } else {
        // ---- pure elementwise: blocks 8..23, 1024 pixels each ----
        const int idx = (blockIdx.x - 8) * 1024 + tid;   // [0, 16384)
        const int b = idx >> 12, n = idx & 4095;
        const int pix = idx;
        const int pslot = idx >> 6;                       // [0,256), one per wave
        const float* ob = outs + (size_t)b * CCH * N;

        const float x  = ob[n];
        const float g  = gconf[pix];
        const float im = ign[pix] > 0 ? 1.f : 0.f;
        const float ff = fg[pix] > 0 ? 1.f : 0.f;

        // focal conf
        const float ls  = logsig(x);
        const float lns = logsig(-x);
        const float bce = -(g * ls + (1.f - g) * lns);
        const float p   = expf(-bce);
        const float conf = -(LINE_W * g * ls + (1.f - g) * lns);
        const float om  = 1.f - p;
        const float focal = om * om * conf * im;

        // dice partials
        const float ps = 1.f / (1.f + expf(-x));
        const float q = 1.f - ps, hh = 1.f - g;
        const float spg = ps * g * im,  spp = ps * ps * im,  sgg = g * g * im;
        const float s2pg = q * hh * im, s2pp = q * q * im,   s2gg = hh * hh * im;

        // offset MSE
        const float sox = 1.f / (1.f + expf(-ob[1 * N + n]));
        const float soy = 1.f / (1.f + expf(-ob[2 * N + n]));
        const float dx = sox - gox[pix], dy = soy - goy[pix];
        const float se = (dx * dx + dy * dy) * ff;

        // cls BCE (8 channels)
        float cl = 0.f;
        #pragma unroll
        for (int c = 0; c < 8; ++c) {
            const float z  = ob[(5 + c) * N + n];
            const float gc = gcls[((size_t)b * 8 + c) * N + n];
            cl += -(gc * logsig(z) + (1.f - gc) * logsig(-z));
        }
        cl *= ff;

        float vals[11] = {spg, spp, sgg, s2pg, s2pp, s2gg, im, focal, se, ff, cl};
        #pragma unroll
        for (int qq = 0; qq < 11; ++qq) {
            const float r = wave_reduce(vals[qq]);
            if (ln == 0) ws[EWP_OFF + qq * 256 + pslot] = r;
        }
    }
}

// ---------------- Kernel 2: pair sums + last-block finalize ----------------
// grid = 2048 (pushall: eb(8)|it(16)|js(16)) + 256 (buckets: bk(64)|js(4))
__global__ __launch_bounds__(256) void pair_kernel(float* __restrict__ ws,
                                                   float* __restrict__ out) {
    const int bx  = blockIdx.x;
    const int tid = threadIdx.x;
    const int ln  = tid & 63;
    const int wv  = tid >> 6;
    const int* curs  = (const int*)(ws + CURS_OFF);
    const int* vcurs = (const int*)(ws + VCURS_OFF);

    float a0 = 0.f, a1 = 0.f, a2 = 0.f, a3 = 0.f;   // r0 = a0+a2, r1 = a1+a3

    if (bx < 2048) {
        // pushall over all valid pairs: hinge max(1-d, 0). NaN pads contribute 0.
        const int eb = bx >> 8, it = (bx >> 4) & 15, js = bx & 15;
        const int m = min(vcurs[eb], 4096);
        if (it * 256 < m) {
            const float* arr = ws + VC_OFF + eb * 4096;
            const float pi = arr[it * 256 + tid];
            const int nch = (m + 63) >> 6;
            for (int cj = js; cj < nch; cj += 16) {
                const float jv = arr[cj * 64 + ln];
                #pragma unroll
                for (int k = 0; k < 64; k += 2) {
                    const float s0 = rdlane(jv, k);
                    const float s1 = rdlane(jv, k + 1);
                    a0 += fmaxf(1.f - fabsf(pi - s0), 0.f);
                    a2 += fmaxf(1.f - fabsf(pi - s1), 0.f);
                }
            }
        }
    } else {
        // per-class buckets: pull hinge max(d-0.5,0) and pushsame hinge max(1-d,0)
        const int bx2 = bx - 2048;            // [0,256)
        const int bk = bx2 >> 2, js = bx2 & 3;
        const int m = min(curs[bk], BCAP);
        const float* arr = ws + BUCK_OFF + bk * BCAP;
        const int nch = (m + 63) >> 6;
        for (int i0 = 0; i0 < m; i0 += 256) {
            const float pi = arr[i0 + tid];   // padded to 256-mult -> in bounds
            for (int cj = js; cj < nch; cj += 4) {
                const float jv = arr[cj * 64 + ln];
                #pragma unroll
                for (int k = 0; k < 64; k += 2) {
                    const float d0 = fabsf(pi - rdlane(jv, k));
                    const float d1 = fabsf(pi - rdlane(jv, k + 1));
                    a0 += fmaxf(d0 - 0.5f, 0.f);   // pull
                    a2 += fmaxf(d1 - 0.5f, 0.f);
                    a1 += fmaxf(1.f - d0, 0.f);    // pushsame
                    a3 += fmaxf(1.f - d1, 0.f);
                }
            }
        }
    }

    // block reduce (s0 = pushall | pull ; s1 = - | pushsame)
    __shared__ float red[4][2];
    __shared__ bool amLast;
    const float r0 = wave_reduce(a0 + a2);
    const float r1 = wave_reduce(a1 + a3);
    if (ln == 0) { red[wv][0] = r0; red[wv][1] = r1; }
    __syncthreads();
    if (tid == 0) {
        const float s0 = red[0][0] + red[1][0] + red[2][0] + red[3][0];
        const float s1 = red[0][1] + red[1][1] + red[2][1] + red[3][1];
        if (bx < 2048) {
            ws[PA_OFF + bx] = s0;
        } else {
            ws[BP_OFF + (bx - 2048) * 2 + 0] = s0;
            ws[BP_OFF + (bx - 2048) * 2 + 1] = s1;
        }
        __threadfence();                              // release partials
        const int old = atomicAdd((int*)(ws + DONE_OFF), 1);
        amLast = (old == NPAIRB - 1);
    }
    __syncthreads();
    if (!amLast) return;
    __threadfence();                                  // acquire all partials

    // ---- finalize (this block only, 256 threads) ----
    __shared__ double ewb[4][7];
    __shared__ double gsum[4];
    __shared__ double pa[8];
    __shared__ double bp[8][2];
    __shared__ double sred[4];

    #pragma unroll
    for (int q = 0; q < 7; ++q) {
        double v = (double)ws[EWP_OFF + q * 256 + tid];
        v = wave_reduce_d(v);
        if (ln == 0) ewb[wv][q] = v;
    }
    for (int q = 7; q < 11; ++q) {
        double v = (double)ws[EWP_OFF + q * 256 + tid];
        v = wave_reduce_d(v);
        if (ln == 0) sred[wv] = v;
        __syncthreads();
        if (tid == 0) gsum[q - 7] = sred[0] + sred[1] + sred[2] + sred[3];
        __syncthreads();
    }
    for (int eb = 0; eb < 8; ++eb) {
        double v = (double)ws[PA_OFF + eb * 256 + tid];
        v = wave_reduce_d(v);
        if (ln == 0) sred[wv] = v;
        __syncthreads();
        if (tid == 0) pa[eb] = sred[0] + sred[1] + sred[2] + sred[3];
        __syncthreads();
    }
    #pragma unroll
    for (int q = 0; q < 2; ++q) {
        double v = (double)ws[BP_OFF + tid * 2 + q];
        #pragma unroll
        for (int off = 16; off > 0; off >>= 1) v += __shfl_down(v, off, 32);
        if ((tid & 31) == 0) bp[tid >> 5][q] = v;
    }
    __syncthreads();
    if (tid != 0) return;

    double ign_sum = 0.0, dice = 0.0;
    for (int b = 0; b < B; ++b) {
        const double msum = ewb[b][6];
        ign_sum += msum;
        const double t = 1.0 - (ewb[b][0] + EPS) / (ewb[b][1] + ewb[b][2] + EPS)
                             - (ewb[b][3] + EPS) / (ewb[b][4] + ewb[b][5] + EPS);
        dice += (msum > 0.0) ? t : 0.0;
    }
    const double focal = gsum[0], se = gsum[1], ffs = gsum[2], clsum = gsum[3];
    const double conf_loss = focal / fmax(ign_sum, 1.0) + DICE_W * dice / B;
    const double off_loss  = se / fmax(2.0 * ffs, 1.0);

    double embv[2] = {0.0, 0.0};
    for (int e = 0; e < 2; ++e)
        for (int b = 0; b < B; ++b) {
            const int eb = e * 4 + b;
            double cs = 0.0, nv = 0.0;
            for (int c = 0; c < 8; ++c) {
                const double x = (double)curs[eb * 8 + c];
                cs += x * x; nv += x;
            }
            const double cd = nv * nv - cs;
            const double pull = bp[eb][0] / fmax(cs, 1.0);
            const double pushsum = pa[eb] - bp[eb][1];
            const double push = (cd > 0.0) ? pushsum / fmax(cd, 1.0) : 0.0;
            embv[e] += pull + push;
        }

    const double cls_loss = clsum / fmax(8.0 * ffs, 1.0);
    const double total = conf_loss + 0.5 * off_loss
                       + embv[0] / B + embv[1] / B + cls_loss;
    out[0] = (float)total;
}

extern "C" void kernel_launch(void* const* d_in, const int* in_sizes, int n_in,
                              void* d_out, int out_size, void* d_ws, size_t ws_size,
                              hipStream_t stream) {
    const float* outs  = (const float*)d_in[0];
    const float* gconf = (const float*)d_in[1];
    const float* gox   = (const float*)d_in[2];
    const float* goy   = (const float*)d_in[3];
    const int*   lidx  = (const int*)d_in[4];
    const int*   ign   = (const int*)d_in[5];
    const int*   fg    = (const int*)d_in[6];
    const int*   lid   = (const int*)d_in[7];
    const float* gcls  = (const float*)d_in[8];
    float* ws = (float*)d_ws;

    prep_kernel<<<24, 1024, 0, stream>>>(outs, gconf, gox, goy, lidx, ign, fg, lid, gcls, ws);
    pair_kernel<<<NPAIRB, 256, 0, stream>>>(ws, (float*)d_out);
}

// Round 7
// 39.684 us; speedup vs baseline: 1.7688x; 1.7688x over previous
//
#include <hip/hip_runtime.h>

// ---- problem constants (match reference) ----
constexpr int B = 4, N = 4096;       // H*W = 64*64
constexpr int CCH = 13;              // 5 + NC
constexpr float LINE_W = 30.0f;
constexpr double EPS = 1e-05;
constexpr double DICE_W = 5.0;
constexpr int BCAP = 1024;           // per-(e,b,class) bucket capacity (expected ~256)
constexpr int PUSHB = 512;           // pushall blocks: eb(8)|it(16)|js(4)
constexpr int NPAIRB = PUSHB + 256;  // + bucket blocks: bk(64)|js(4)

// ---- ws layout (float-indexed) ----
constexpr int EWP_OFF   = 0;                      // [11][256] elemwise per-wave partials
constexpr int PA_OFF    = 2816;                   // [8][64] pushall per-block partials
constexpr int BP_OFF    = 3328;                   // [256][2] bucket per-block partials (pull, pushsame)
constexpr int CURS_OFF  = 3840;                   // [64] int class histograms
constexpr int VCURS_OFF = 3904;                   // [8] int valid counts
constexpr int BUCK_OFF  = 4096;                   // [64][BCAP] class buckets (NaN padded to 256-mult)
constexpr int VC_OFF    = BUCK_OFF + 64 * BCAP;   // [8][4096] compact valid values (NaN padded)

__device__ inline float logsig(float x) {
    return fminf(x, 0.f) - log1pf(expf(-fabsf(x)));
}
__device__ inline float wave_reduce(float v) {
    #pragma unroll
    for (int off = 32; off > 0; off >>= 1) v += __shfl_down(v, off, 64);
    return v;
}
__device__ inline double wave_reduce_d(double v) {
    #pragma unroll
    for (int off = 32; off > 0; off >>= 1) v += __shfl_down(v, off, 64);
    return v;
}
__device__ inline float rdlane(float v, int k) {
    return __uint_as_float(__builtin_amdgcn_readlane(__float_as_uint(v), k));
}

// ---------------- Kernel 1: compact (blocks 0..7) + elementwise (blocks 8..23) ---
__global__ __launch_bounds__(1024) void prep_kernel(
        const float* __restrict__ outs, const float* __restrict__ gconf,
        const float* __restrict__ gox,  const float* __restrict__ goy,
        const int*   __restrict__ lidx, const int*   __restrict__ ign,
        const int*   __restrict__ fg,   const int*   __restrict__ lid,
        const float* __restrict__ gcls, float* __restrict__ ws) {
    const int tid = threadIdx.x, ln = tid & 63;

    if (blockIdx.x < 8) {
        // ---- compaction/bucketing for eb = blockIdx.x ----
        const int eb = blockIdx.x, e = eb >> 2, b = eb & 3;
        const int* gsrc = e ? lid : lidx;
        const float* pch = outs + ((size_t)b * CCH + 3 + e) * N;

        __shared__ int lcurs[9];            // 8 class cursors + 1 valid cursor
        if (tid < 9) lcurs[tid] = 0;
        __syncthreads();

        #pragma unroll
        for (int it = 0; it < 4; ++it) {
            const int n = it * 1024 + tid;
            const bool v = fg[b * N + n] > 0;
            const float val = pch[n];
            const int cc = gsrc[b * N + n] & 7;
            const unsigned long long below = (1ull << ln) - 1ull;
            const unsigned long long vm = __ballot(v);

            int mycnt = 0;      // lanes 0..7: class counts; lane 8: valid count
            int myrank = 0;     // this thread's rank within its class mask
            #pragma unroll
            for (int c = 0; c < 8; ++c) {
                const unsigned long long m = __ballot(v && cc == c);
                const int cnt = __popcll(m);
                if (ln == c) mycnt = cnt;
                if (cc == c) myrank = __popcll(m & below);
            }
            if (ln == 8) mycnt = __popcll(vm);
            const int myvrank = __popcll(vm & below);

            int abase = 0;
            if (ln < 9) abase = atomicAdd(&lcurs[ln], mycnt);   // 9 lanes, parallel banks
            const int cbase = __shfl(abase, cc, 64);
            const int vbase = __shfl(abase, 8, 64);

            if (v) {
                ws[VC_OFF + eb * 4096 + vbase + myvrank] = val;
                const int slot = cbase + myrank;
                if (slot < BCAP) ws[BUCK_OFF + (eb * 8 + cc) * BCAP + slot] = val;
            }
        }
        __syncthreads();

        // publish cursors + NaN-pad tails up to next 256 multiple
        int* curs  = (int*)(ws + CURS_OFF);
        int* vcurs = (int*)(ws + VCURS_OFF);
        const float QNAN = __int_as_float(0x7FC00000);
        if (tid < 8) curs[eb * 8 + tid] = min(lcurs[tid], BCAP);
        if (tid == 8) vcurs[eb] = lcurs[8];
        #pragma unroll
        for (int c = 0; c < 8; ++c) {
            const int mm = min(lcurs[c], BCAP);
            const int pad = ((mm + 255) & ~255) - mm;
            if (tid < pad) ws[BUCK_OFF + (eb * 8 + c) * BCAP + mm + tid] = QNAN;
        }
        const int mv = lcurs[8];
        const int padv = ((mv + 255) & ~255) - mv;
        if (tid < padv && mv + tid < 4096) ws[VC_OFF + eb * 4096 + mv + tid] = QNAN;
    } else {
        // ---- pure elementwise: blocks 8..23, 1024 pixels each ----
        const int idx = (blockIdx.x - 8) * 1024 + tid;   // [0, 16384)
        const int b = idx >> 12, n = idx & 4095;
        const int pix = idx;
        const int pslot = idx >> 6;                       // [0,256), one per wave
        const float* ob = outs + (size_t)b * CCH * N;

        const float x  = ob[n];
        const float g  = gconf[pix];
        const float im = ign[pix] > 0 ? 1.f : 0.f;
        const float ff = fg[pix] > 0 ? 1.f : 0.f;

        // focal conf
        const float ls  = logsig(x);
        const float lns = logsig(-x);
        const float bce = -(g * ls + (1.f - g) * lns);
        const float p   = expf(-bce);
        const float conf = -(LINE_W * g * ls + (1.f - g) * lns);
        const float om  = 1.f - p;
        const float focal = om * om * conf * im;

        // dice partials
        const float ps = 1.f / (1.f + expf(-x));
        const float q = 1.f - ps, hh = 1.f - g;
        const float spg = ps * g * im,  spp = ps * ps * im,  sgg = g * g * im;
        const float s2pg = q * hh * im, s2pp = q * q * im,   s2gg = hh * hh * im;

        // offset MSE
        const float sox = 1.f / (1.f + expf(-ob[1 * N + n]));
        const float soy = 1.f / (1.f + expf(-ob[2 * N + n]));
        const float dx = sox - gox[pix], dy = soy - goy[pix];
        const float se = (dx * dx + dy * dy) * ff;

        // cls BCE (8 channels)
        float cl = 0.f;
        #pragma unroll
        for (int c = 0; c < 8; ++c) {
            const float z  = ob[(5 + c) * N + n];
            const float gc = gcls[((size_t)b * 8 + c) * N + n];
            cl += -(gc * logsig(z) + (1.f - gc) * logsig(-z));
        }
        cl *= ff;

        float vals[11] = {spg, spp, sgg, s2pg, s2pp, s2gg, im, focal, se, ff, cl};
        #pragma unroll
        for (int qq = 0; qq < 11; ++qq) {
            const float r = wave_reduce(vals[qq]);
            if (ln == 0) ws[EWP_OFF + qq * 256 + pslot] = r;
        }
    }
}

// ---------------- Kernel 2: pair sums (no fences, no atomics) ----------------
// grid = 512 (pushall: eb(8)|it(16)|js(4)) + 256 (buckets: bk(64)|js(4))
__global__ __launch_bounds__(256) void pair_kernel(float* __restrict__ ws) {
    const int bx  = blockIdx.x;
    const int tid = threadIdx.x;
    const int ln  = tid & 63;
    const int wv  = tid >> 6;
    const int* curs  = (const int*)(ws + CURS_OFF);
    const int* vcurs = (const int*)(ws + VCURS_OFF);

    float a0 = 0.f, a1 = 0.f, a2 = 0.f, a3 = 0.f;   // r0 = a0+a2, r1 = a1+a3

    if (bx < PUSHB) {
        // pushall over all valid pairs: hinge max(1-d, 0). NaN pads contribute 0.
        const int eb = bx >> 6, it = (bx >> 2) & 15, js = bx & 3;
        const int m = min(vcurs[eb], 4096);
        if (it * 256 < m) {
            const float* arr = ws + VC_OFF + eb * 4096;
            const float pi = arr[it * 256 + tid];
            const int nch = (m + 63) >> 6;
            for (int cj = js; cj < nch; cj += 4) {
                const float jv = arr[cj * 64 + ln];
                #pragma unroll
                for (int k = 0; k < 64; k += 2) {
                    const float s0 = rdlane(jv, k);
                    const float s1 = rdlane(jv, k + 1);
                    a0 += fmaxf(1.f - fabsf(pi - s0), 0.f);
                    a2 += fmaxf(1.f - fabsf(pi - s1), 0.f);
                }
            }
        }
    } else {
        // per-class buckets: pull hinge max(d-0.5,0) and pushsame hinge max(1-d,0)
        const int bx2 = bx - PUSHB;           // [0,256)
        const int bk = bx2 >> 2, js = bx2 & 3;
        const int m = min(curs[bk], BCAP);
        const float* arr = ws + BUCK_OFF + bk * BCAP;
        const int nch = (m + 63) >> 6;
        for (int i0 = 0; i0 < m; i0 += 256) {
            const float pi = arr[i0 + tid];   // padded to 256-mult -> in bounds
            for (int cj = js; cj < nch; cj += 4) {
                const float jv = arr[cj * 64 + ln];
                #pragma unroll
                for (int k = 0; k < 64; k += 2) {
                    const float d0 = fabsf(pi - rdlane(jv, k));
                    const float d1 = fabsf(pi - rdlane(jv, k + 1));
                    a0 += fmaxf(d0 - 0.5f, 0.f);   // pull
                    a2 += fmaxf(d1 - 0.5f, 0.f);
                    a1 += fmaxf(1.f - d0, 0.f);    // pushsame
                    a3 += fmaxf(1.f - d1, 0.f);
                }
            }
        }
    }

    // block reduce (s0 = pushall | pull ; s1 = - | pushsame)
    __shared__ float red[4][2];
    const float r0 = wave_reduce(a0 + a2);
    const float r1 = wave_reduce(a1 + a3);
    if (ln == 0) { red[wv][0] = r0; red[wv][1] = r1; }
    __syncthreads();
    if (tid == 0) {
        const float s0 = red[0][0] + red[1][0] + red[2][0] + red[3][0];
        const float s1 = red[0][1] + red[1][1] + red[2][1] + red[3][1];
        if (bx < PUSHB) {
            ws[PA_OFF + bx] = s0;                       // [eb][64] layout
        } else {
            ws[BP_OFF + (bx - PUSHB) * 2 + 0] = s0;
            ws[BP_OFF + (bx - PUSHB) * 2 + 1] = s1;
        }
    }
}

// ---------------- Kernel 3: finalize (1 block, 256 threads) ----------------
__global__ __launch_bounds__(256) void finalize_kernel(
        const float* __restrict__ ws, float* __restrict__ out) {
    const int tid = threadIdx.x, ln = tid & 63, wv = tid >> 6;
    __shared__ double ewb[4][7];   // per-batch dice partials + msum
    __shared__ double gsum[4];     // focal, se, fg, cls
    __shared__ double pa[8];
    __shared__ double bp[8][2];
    __shared__ double sred[4];

    // per-batch rows (wave wv <-> batch wv)
    #pragma unroll
    for (int q = 0; q < 7; ++q) {
        double v = (double)ws[EWP_OFF + q * 256 + tid];
        v = wave_reduce_d(v);
        if (ln == 0) ewb[wv][q] = v;
    }
    // global rows
    for (int q = 7; q < 11; ++q) {
        double v = (double)ws[EWP_OFF + q * 256 + tid];
        v = wave_reduce_d(v);
        if (ln == 0) sred[wv] = v;
        __syncthreads();
        if (tid == 0) gsum[q - 7] = sred[0] + sred[1] + sred[2] + sred[3];
        __syncthreads();
    }
    // pushall: wave wv reduces ebs 2wv and 2wv+1 (64 partials each)
    #pragma unroll
    for (int q = 0; q < 2; ++q) {
        const int eb = wv * 2 + q;
        double v = (double)ws[PA_OFF + eb * 64 + ln];
        v = wave_reduce_d(v);
        if (ln == 0) pa[eb] = v;
    }
    // bucket partials: 32 consecutive slots per eb (eb = tid>>5)
    #pragma unroll
    for (int q = 0; q < 2; ++q) {
        double v = (double)ws[BP_OFF + tid * 2 + q];
        #pragma unroll
        for (int off = 16; off > 0; off >>= 1) v += __shfl_down(v, off, 32);
        if ((tid & 31) == 0) bp[tid >> 5][q] = v;
    }
    __syncthreads();
    if (tid != 0) return;

    const int* curs = (const int*)(ws + CURS_OFF);

    double ign_sum = 0.0, dice = 0.0;
    for (int b = 0; b < B; ++b) {
        const double msum = ewb[b][6];
        ign_sum += msum;
        const double t = 1.0 - (ewb[b][0] + EPS) / (ewb[b][1] + ewb[b][2] + EPS)
                             - (ewb[b][3] + EPS) / (ewb[b][4] + ewb[b][5] + EPS);
        dice += (msum > 0.0) ? t : 0.0;
    }
    const double focal = gsum[0], se = gsum[1], ffs = gsum[2], clsum = gsum[3];
    const double conf_loss = focal / fmax(ign_sum, 1.0) + DICE_W * dice / B;
    const double off_loss  = se / fmax(2.0 * ffs, 1.0);

    double embv[2] = {0.0, 0.0};
    for (int e = 0; e < 2; ++e)
        for (int b = 0; b < B; ++b) {
            const int eb = e * 4 + b;
            double cs = 0.0, nv = 0.0;
            for (int c = 0; c < 8; ++c) {
                const double x = (double)curs[eb * 8 + c];
                cs += x * x; nv += x;
            }
            const double cd = nv * nv - cs;
            const double pull = bp[eb][0] / fmax(cs, 1.0);
            const double pushsum = pa[eb] - bp[eb][1];
            const double push = (cd > 0.0) ? pushsum / fmax(cd, 1.0) : 0.0;
            embv[e] += pull + push;
        }

    const double cls_loss = clsum / fmax(8.0 * ffs, 1.0);
    const double total = conf_loss + 0.5 * off_loss
                       + embv[0] / B + embv[1] / B + cls_loss;
    out[0] = (float)total;
}

extern "C" void kernel_launch(void* const* d_in, const int* in_sizes, int n_in,
                              void* d_out, int out_size, void* d_ws, size_t ws_size,
                              hipStream_t stream) {
    const float* outs  = (const float*)d_in[0];
    const float* gconf = (const float*)d_in[1];
    const float* gox   = (const float*)d_in[2];
    const float* goy   = (const float*)d_in[3];
    const int*   lidx  = (const int*)d_in[4];
    const int*   ign   = (const int*)d_in[5];
    const int*   fg    = (const int*)d_in[6];
    const int*   lid   = (const int*)d_in[7];
    const float* gcls  = (const float*)d_in[8];
    float* ws = (float*)d_ws;

    prep_kernel<<<24, 1024, 0, stream>>>(outs, gconf, gox, goy, lidx, ign, fg, lid, gcls, ws);
    pair_kernel<<<NPAIRB, 256, 0, stream>>>(ws);
    finalize_kernel<<<1, 256, 0, stream>>>(ws, (float*)d_out);
}

// Round 8
// 33.869 us; speedup vs baseline: 2.0725x; 1.1717x over previous
//
#include <hip/hip_runtime.h>

// ---- problem constants (match reference) ----
constexpr int B = 4, N = 4096;       // H*W = 64*64
constexpr int CCH = 13;              // 5 + NC
constexpr float LINE_W = 30.0f;
constexpr double EPS = 1e-05;
constexpr double DICE_W = 5.0;

constexpr int PUSH_SL = 32;                    // pushall slices per eb
constexpr int PUSHB = 8 * PUSH_SL;             // 256 pushall blocks
constexpr int BUCKB = 64;                      // one per (eb, class)
constexpr int ELEMB = 64;                      // 16384 px / 256
constexpr int NB = PUSHB + BUCKB + ELEMB;      // 384 blocks

// ---- ws layout (float-indexed) ----
constexpr int EWP_OFF  = 0;        // [11][256] elemwise per-wave partials
constexpr int PA_OFF   = 2816;     // [256] pushall per-block partials (eb*32+js)
constexpr int BP_OFF   = 3072;     // [64][2] bucket partials (pull, pushsame)
constexpr int CURS_OFF = 3200;     // [64] int class histograms

__device__ inline float logsig(float x) {
    return fminf(x, 0.f) - log1pf(expf(-fabsf(x)));
}
__device__ inline float wave_reduce(float v) {
    #pragma unroll
    for (int off = 32; off > 0; off >>= 1) v += __shfl_down(v, off, 64);
    return v;
}
__device__ inline double wave_reduce_d(double v) {
    #pragma unroll
    for (int off = 32; off > 0; off >>= 1) v += __shfl_down(v, off, 64);
    return v;
}
__device__ inline float rdlane(float v, int k) {
    return __uint_as_float(__builtin_amdgcn_readlane(__float_as_uint(v), k));
}

// ---------------- Kernel 1: self-compacting pair blocks + elemwise blocks ----
// bx [0,256):   pushall. eb=bx>>5, js=bx&31. Compact valid vals of eb into LDS,
//               then 1/32 of the all-pairs push hinge.
// bx [256,320): bucket. bk=bx-256 -> (eb=bk>>3, c=bk&7). Compact class-c vals,
//               full pull + pushsame over the class pairs; publish histogram.
// bx [320,384): elementwise, 256 px/block.
__global__ __launch_bounds__(256) void fused_kernel(
        const float* __restrict__ outs, const float* __restrict__ gconf,
        const float* __restrict__ gox,  const float* __restrict__ goy,
        const int*   __restrict__ lidx, const int*   __restrict__ ign,
        const int*   __restrict__ fg,   const int*   __restrict__ lid,
        const float* __restrict__ gcls, float* __restrict__ ws) {
    const int bx = blockIdx.x, tid = threadIdx.x;
    const int ln = tid & 63, wv = tid >> 6;

    __shared__ float sv[4096];
    __shared__ unsigned long long smask[16][4];
    __shared__ int scnt[64];
    __shared__ int sbase[64];
    __shared__ int stot;
    __shared__ float red[4][2];

    if (bx < PUSHB + BUCKB) {
        const bool isPush = bx < PUSHB;
        const int eb  = isPush ? (bx >> 5) : ((bx - PUSHB) >> 3);
        const int cls = isPush ? -1 : ((bx - PUSHB) & 7);
        const int js  = isPush ? (bx & 31) : 0;
        const int e = eb >> 2, b = eb & 3;
        const float* pch = outs + ((size_t)b * CCH + 3 + e) * N;
        const int* fgp = fg + b * N;
        const int* gp  = (e ? lid : lidx) + b * N;

        // ---- phase 1: predicate ballots + per-(chunk,wave) counts ----
        unsigned pred = 0;
        float vals[16];
        #pragma unroll
        for (int ch = 0; ch < 16; ++ch) {
            const int n = ch * 256 + tid;
            bool v = fgp[n] > 0;
            if (!isPush) v = v && ((gp[n] & 7) == cls);
            vals[ch] = pch[n];
            const unsigned long long mk = __ballot(v);
            pred |= (v ? 1u : 0u) << ch;
            if (ln == 0) { smask[ch][wv] = mk; scnt[ch * 4 + wv] = __popcll(mk); }
        }
        __syncthreads();

        // ---- exclusive scan over 64 segment counts (one wave) ----
        if (tid < 64) {
            const int c = scnt[tid];
            int inc = c;
            #pragma unroll
            for (int off = 1; off < 64; off <<= 1) {
                const int t = __shfl_up(inc, off, 64);
                if (ln >= off) inc += t;
            }
            sbase[tid] = inc - c;
            if (tid == 63) stot = inc;
        }
        __syncthreads();
        const int m = min(stot, 4096);

        // ---- phase 2: scatter by rank + NaN-pad to 256 multiple ----
        #pragma unroll
        for (int ch = 0; ch < 16; ++ch) {
            if ((pred >> ch) & 1u) {
                const unsigned long long mk = smask[ch][wv];
                const int slot = sbase[ch * 4 + wv] + __popcll(mk & ((1ull << ln) - 1ull));
                if (slot < 4096) sv[slot] = vals[ch];
            }
        }
        const int mpad = (m + 255) & ~255;
        for (int i = m + tid; i < mpad; i += 256) sv[i] = __int_as_float(0x7FC00000);
        __syncthreads();

        // ---- pair sums over LDS ----
        float a0 = 0.f, a1 = 0.f, a2 = 0.f, a3 = 0.f;
        const int nch = (m + 63) >> 6;
        if (isPush) {
            for (int i0 = 0; i0 < m; i0 += 256) {
                const float pi = sv[i0 + tid];
                for (int cj = js; cj < nch; cj += PUSH_SL) {
                    const float jv = sv[cj * 64 + ln];
                    #pragma unroll
                    for (int k = 0; k < 64; k += 2) {
                        const float s0 = rdlane(jv, k);
                        const float s1 = rdlane(jv, k + 1);
                        a0 += fmaxf(1.f - fabsf(pi - s0), 0.f);
                        a2 += fmaxf(1.f - fabsf(pi - s1), 0.f);
                    }
                }
            }
        } else {
            for (int i0 = 0; i0 < m; i0 += 256) {
                const float pi = sv[i0 + tid];
                for (int cj = 0; cj < nch; ++cj) {
                    const float jv = sv[cj * 64 + ln];
                    #pragma unroll
                    for (int k = 0; k < 64; k += 2) {
                        const float d0 = fabsf(pi - rdlane(jv, k));
                        const float d1 = fabsf(pi - rdlane(jv, k + 1));
                        a0 += fmaxf(d0 - 0.5f, 0.f);   // pull
                        a2 += fmaxf(d1 - 0.5f, 0.f);
                        a1 += fmaxf(1.f - d0, 0.f);    // pushsame
                        a3 += fmaxf(1.f - d1, 0.f);
                    }
                }
            }
        }

        // ---- block reduce + publish ----
        const float r0 = wave_reduce(a0 + a2);
        const float r1 = wave_reduce(a1 + a3);
        if (ln == 0) { red[wv][0] = r0; red[wv][1] = r1; }
        __syncthreads();
        if (tid == 0) {
            const float s0 = red[0][0] + red[1][0] + red[2][0] + red[3][0];
            const float s1 = red[0][1] + red[1][1] + red[2][1] + red[3][1];
            if (isPush) {
                ws[PA_OFF + bx] = s0;
            } else {
                const int bk = bx - PUSHB;
                ws[BP_OFF + bk * 2 + 0] = s0;
                ws[BP_OFF + bk * 2 + 1] = s1;
                ((int*)(ws + CURS_OFF))[bk] = m;
            }
        }
    } else {
        // ---- elementwise: 256 px per block ----
        const int blk = bx - (PUSHB + BUCKB);
        const int idx = blk * 256 + tid;           // [0, 16384)
        const int b = idx >> 12, n = idx & 4095;
        const int pix = idx;
        const int pslot = idx >> 6;                // [0,256)
        const float* ob = outs + (size_t)b * CCH * N;

        const float x  = ob[n];
        const float g  = gconf[pix];
        const float im = ign[pix] > 0 ? 1.f : 0.f;
        const float ff = fg[pix] > 0 ? 1.f : 0.f;

        const float ls  = logsig(x);
        const float lns = logsig(-x);
        const float bce = -(g * ls + (1.f - g) * lns);
        const float p   = expf(-bce);
        const float conf = -(LINE_W * g * ls + (1.f - g) * lns);
        const float om  = 1.f - p;
        const float focal = om * om * conf * im;

        const float ps = 1.f / (1.f + expf(-x));
        const float q = 1.f - ps, hh = 1.f - g;
        const float spg = ps * g * im,  spp = ps * ps * im,  sgg = g * g * im;
        const float s2pg = q * hh * im, s2pp = q * q * im,   s2gg = hh * hh * im;

        const float sox = 1.f / (1.f + expf(-ob[1 * N + n]));
        const float soy = 1.f / (1.f + expf(-ob[2 * N + n]));
        const float dx = sox - gox[pix], dy = soy - goy[pix];
        const float se = (dx * dx + dy * dy) * ff;

        float cl = 0.f;
        #pragma unroll
        for (int c = 0; c < 8; ++c) {
            const float z  = ob[(5 + c) * N + n];
            const float gc = gcls[((size_t)b * 8 + c) * N + n];
            cl += -(gc * logsig(z) + (1.f - gc) * logsig(-z));
        }
        cl *= ff;

        float vals[11] = {spg, spp, sgg, s2pg, s2pp, s2gg, im, focal, se, ff, cl};
        #pragma unroll
        for (int qq = 0; qq < 11; ++qq) {
            const float r = wave_reduce(vals[qq]);
            if (ln == 0) ws[EWP_OFF + qq * 256 + pslot] = r;
        }
    }
}

// ---------------- Kernel 2: finalize (1 block, 256 threads) ----------------
__global__ __launch_bounds__(256) void finalize_kernel(
        const float* __restrict__ ws, float* __restrict__ out) {
    const int tid = threadIdx.x, ln = tid & 63, wv = tid >> 6;
    __shared__ double ewb[4][7];
    __shared__ double gsum[4];
    __shared__ double pa[8];
    __shared__ double bp[8][2];
    __shared__ double sred[4];

    #pragma unroll
    for (int q = 0; q < 7; ++q) {
        double v = (double)ws[EWP_OFF + q * 256 + tid];
        v = wave_reduce_d(v);
        if (ln == 0) ewb[wv][q] = v;
    }
    for (int q = 7; q < 11; ++q) {
        double v = (double)ws[EWP_OFF + q * 256 + tid];
        v = wave_reduce_d(v);
        if (ln == 0) sred[wv] = v;
        __syncthreads();
        if (tid == 0) gsum[q - 7] = sred[0] + sred[1] + sred[2] + sred[3];
        __syncthreads();
    }
    // pushall partials: PA[256], slot = eb*32 + js -> reduce per 32
    {
        double v = (double)ws[PA_OFF + tid];
        #pragma unroll
        for (int off = 16; off > 0; off >>= 1) v += __shfl_down(v, off, 32);
        if ((tid & 31) == 0) pa[tid >> 5] = v;
    }
    // bucket partials: BP[64][2] -> reduce per 8 (per eb)
    if (tid < 64) {
        double v0 = (double)ws[BP_OFF + tid * 2 + 0];
        double v1 = (double)ws[BP_OFF + tid * 2 + 1];
        #pragma unroll
        for (int off = 4; off > 0; off >>= 1) {
            v0 += __shfl_down(v0, off, 8);
            v1 += __shfl_down(v1, off, 8);
        }
        if ((tid & 7) == 0) { bp[tid >> 3][0] = v0; bp[tid >> 3][1] = v1; }
    }
    __syncthreads();
    if (tid != 0) return;

    const int* curs = (const int*)(ws + CURS_OFF);

    double ign_sum = 0.0, dice = 0.0;
    for (int b = 0; b < B; ++b) {
        const double msum = ewb[b][6];
        ign_sum += msum;
        const double t = 1.0 - (ewb[b][0] + EPS) / (ewb[b][1] + ewb[b][2] + EPS)
                             - (ewb[b][3] + EPS) / (ewb[b][4] + ewb[b][5] + EPS);
        dice += (msum > 0.0) ? t : 0.0;
    }
    const double focal = gsum[0], se = gsum[1], ffs = gsum[2], clsum = gsum[3];
    const double conf_loss = focal / fmax(ign_sum, 1.0) + DICE_W * dice / B;
    const double off_loss  = se / fmax(2.0 * ffs, 1.0);

    double embv[2] = {0.0, 0.0};
    for (int e = 0; e < 2; ++e)
        for (int b = 0; b < B; ++b) {
            const int eb = e * 4 + b;
            double cs = 0.0, nv = 0.0;
            for (int c = 0; c < 8; ++c) {
                const double x = (double)curs[eb * 8 + c];
                cs += x * x; nv += x;
            }
            const double cd = nv * nv - cs;
            const double pull = bp[eb][0] / fmax(cs, 1.0);
            const double pushsum = pa[eb] - bp[eb][1];
            const double push = (cd > 0.0) ? pushsum / fmax(cd, 1.0) : 0.0;
            embv[e] += pull + push;
        }

    const double cls_loss = clsum / fmax(8.0 * ffs, 1.0);
    const double total = conf_loss + 0.5 * off_loss
                       + embv[0] / B + embv[1] / B + cls_loss;
    out[0] = (float)total;
}

extern "C" void kernel_launch(void* const* d_in, const int* in_sizes, int n_in,
                              void* d_out, int out_size, void* d_ws, size_t ws_size,
                              hipStream_t stream) {
    const float* outs  = (const float*)d_in[0];
    const float* gconf = (const float*)d_in[1];
    const float* gox   = (const float*)d_in[2];
    const float* goy   = (const float*)d_in[3];
    const int*   lidx  = (const int*)d_in[4];
    const int*   ign   = (const int*)d_in[5];
    const int*   fg    = (const int*)d_in[6];
    const int*   lid   = (const int*)d_in[7];
    const float* gcls  = (const float*)d_in[8];
    float* ws = (float*)d_ws;

    fused_kernel<<<NB, 256, 0, stream>>>(outs, gconf, gox, goy, lidx, ign, fg, lid, gcls, ws);
    finalize_kernel<<<1, 256, 0, stream>>>(ws, (float*)d_out);
}